// Round 9
// baseline (860.858 us; speedup 1.0000x reference)
//
#include <hip/hip_runtime.h>

#define NC 100352       // N*C = 196*512
typedef unsigned long long ull;

// ---------------------------------------------------------------------------
// QKV GEMM: 256x128 tile, BK=16, 256 threads, 16x8 microtile (rows split
// 4x4 at +64 strides -> conflict-free b128). Single-buffered LDS, 2 barriers
// per BK step (round-2/8 loop shape, low reg pressure). NO launch_bounds
// min-waves clamp: rounds 4/6 proved the clamp causes catastrophic spill;
// target ~200 VGPR, 2 waves/SIMD, 2 resident blocks/CU.
// LDS math: 6 b128 / 256 SIMD-cy per wave-k -> VALU cap 89% (vs 67% at 8x8).
// Accumulation: k-ascending sequential fmaf per output -> bit-identical
// (absmax 0.0, rounds 1-8; same row mapping as round-4's validated kernel).
// Grid 392*NMAT, XCD-bijective swizzle (12 consecutive w share an A panel).
// ---------------------------------------------------------------------------
template <int NMAT, bool BIAS>
__global__ __launch_bounds__(256) void gemm16(
    const float* __restrict__ A,
    const float* __restrict__ W0, const float* __restrict__ W1,
    const float* __restrict__ W2, const float* __restrict__ bias,
    float* __restrict__ C0, float* __restrict__ C1, float* __restrict__ C2)
{
    __shared__ float As[16][260];   // 16,640 B
    __shared__ float Bs[16][132];   //  8,448 B (25.1 KB total)

    const int chunk = (NMAT * 392) >> 3;
    const int w = ((int)blockIdx.x & 7) * chunk + ((int)blockIdx.x >> 3);
    const int rp = w / (4 * NMAT);                 // row panel 0..97
    const int rem = w - rp * (4 * NMAT);
    const int br = rem >> 2;
    const int cb = rem & 3;

    const float* Wb = (NMAT == 1 || br == 0) ? W0 : (br == 1 ? W1 : W2);
    float* Cb = (NMAT == 1 || br == 0) ? C0 : (br == 1 ? C1 : C2);

    const int tid = threadIdx.x;
    const int r0 = tid >> 2;          // 0..63 staging row base
    const int kq = (tid & 3) << 2;    // 0,4,8,12 staging k offset
    const int rg = (tid >> 4) << 2;   // compute row base 0..60
    const int cg = (tid & 15) << 2;   // compute col base 0..60

    float acc[16][8] = {};
    const float* Ap = A + (size_t)(rp * 256 + r0) * 512 + kq;
    const float* Bp = Wb + (size_t)(cb * 128 + r0) * 512 + kq;

    for (int k0 = 0; k0 < 512; k0 += 16) {
        float4 a[4], b[2];
#pragma unroll
        for (int s = 0; s < 4; ++s)
            a[s] = *(const float4*)(Ap + (size_t)s * 64 * 512 + k0);
#pragma unroll
        for (int s = 0; s < 2; ++s)
            b[s] = *(const float4*)(Bp + (size_t)s * 64 * 512 + k0);
        __syncthreads();  // previous iteration's LDS reads done
#pragma unroll
        for (int s = 0; s < 4; ++s) {
            As[kq + 0][r0 + s * 64] = a[s].x;
            As[kq + 1][r0 + s * 64] = a[s].y;
            As[kq + 2][r0 + s * 64] = a[s].z;
            As[kq + 3][r0 + s * 64] = a[s].w;
        }
#pragma unroll
        for (int s = 0; s < 2; ++s) {
            Bs[kq + 0][r0 + s * 64] = b[s].x;
            Bs[kq + 1][r0 + s * 64] = b[s].y;
            Bs[kq + 2][r0 + s * 64] = b[s].z;
            Bs[kq + 3][r0 + s * 64] = b[s].w;
        }
        __syncthreads();
#pragma unroll
        for (int k = 0; k < 16; ++k) {
            float av[16], bv[8];
#pragma unroll
            for (int s = 0; s < 4; ++s)
                *(float4*)&av[s * 4] = *(const float4*)&As[k][rg + s * 64];
#pragma unroll
            for (int s = 0; s < 2; ++s)
                *(float4*)&bv[s * 4] = *(const float4*)&Bs[k][cg + s * 64];
#pragma unroll
            for (int i = 0; i < 16; ++i)
#pragma unroll
                for (int j = 0; j < 8; ++j)
                    acc[i][j] = fmaf(av[i], bv[j], acc[i][j]);
        }
    }

#pragma unroll
    for (int s = 0; s < 4; ++s)
#pragma unroll
        for (int i = 0; i < 4; ++i) {
            const int row = rp * 256 + s * 64 + rg + i;
#pragma unroll
            for (int jh = 0; jh < 2; ++jh) {
                const int col = cb * 128 + cg + jh * 64;
                float4 o;
                o.x = acc[s * 4 + i][jh * 4 + 0];
                o.y = acc[s * 4 + i][jh * 4 + 1];
                o.z = acc[s * 4 + i][jh * 4 + 2];
                o.w = acc[s * 4 + i][jh * 4 + 3];
                if (BIAS) {
                    o.x += bias[col + 0]; o.y += bias[col + 1];
                    o.z += bias[col + 2]; o.w += bias[col + 3];
                }
                *(float4*)&Cb[(size_t)row * 512 + col] = o;
            }
        }
}

// ---------------------------------------------------------------------------
// proj GEMM: round-8 8x8 body unchanged (784-block grid suits it).
// ---------------------------------------------------------------------------
template <int NMAT, bool BIAS>
__global__ __launch_bounds__(256) void gemm_nt(
    const float* __restrict__ A,
    const float* __restrict__ W0, const float* __restrict__ W1,
    const float* __restrict__ W2, const float* __restrict__ bias,
    float* __restrict__ C0, float* __restrict__ C1, float* __restrict__ C2)
{
    __shared__ float As[16][132];
    __shared__ float Bs[16][132];

    const int chunk = (NMAT * 784) >> 3;
    const int w = ((int)blockIdx.x & 7) * chunk + ((int)blockIdx.x >> 3);
    const int rp = w / (4 * NMAT);
    const int rem = w - rp * (4 * NMAT);
    const int br = rem >> 2;
    const int cb = rem & 3;

    const float* Wb = (NMAT == 1 || br == 0) ? W0 : (br == 1 ? W1 : W2);
    float* Cb = (NMAT == 1 || br == 0) ? C0 : (br == 1 ? C1 : C2);

    const int tid = threadIdx.x;
    const int r0 = tid >> 2;
    const int kq = (tid & 3) << 2;
    const int rg = (tid >> 4) << 2;
    const int cg = (tid & 15) << 2;

    float acc[8][8] = {};
    const float* A0 = A + (size_t)(rp * 128 + r0) * 512 + kq;
    const float* A1 = A0 + (size_t)64 * 512;
    const float* B0 = Wb + (size_t)(cb * 128 + r0) * 512 + kq;
    const float* B1 = B0 + (size_t)64 * 512;

    for (int k0 = 0; k0 < 512; k0 += 16) {
        const float4 a0 = *(const float4*)(A0 + k0);
        const float4 a1 = *(const float4*)(A1 + k0);
        const float4 b0 = *(const float4*)(B0 + k0);
        const float4 b1 = *(const float4*)(B1 + k0);
        __syncthreads();
        As[kq + 0][r0] = a0.x; As[kq + 1][r0] = a0.y; As[kq + 2][r0] = a0.z; As[kq + 3][r0] = a0.w;
        As[kq + 0][r0 + 64] = a1.x; As[kq + 1][r0 + 64] = a1.y; As[kq + 2][r0 + 64] = a1.z; As[kq + 3][r0 + 64] = a1.w;
        Bs[kq + 0][r0] = b0.x; Bs[kq + 1][r0] = b0.y; Bs[kq + 2][r0] = b0.z; Bs[kq + 3][r0] = b0.w;
        Bs[kq + 0][r0 + 64] = b1.x; Bs[kq + 1][r0 + 64] = b1.y; Bs[kq + 2][r0 + 64] = b1.z; Bs[kq + 3][r0 + 64] = b1.w;
        __syncthreads();
#pragma unroll
        for (int k = 0; k < 16; ++k) {
            float av[8], bv[8];
            *(float4*)&av[0] = *(const float4*)&As[k][rg];
            *(float4*)&av[4] = *(const float4*)&As[k][rg + 64];
            *(float4*)&bv[0] = *(const float4*)&Bs[k][cg];
            *(float4*)&bv[4] = *(const float4*)&Bs[k][cg + 64];
#pragma unroll
            for (int i = 0; i < 8; ++i)
#pragma unroll
                for (int j = 0; j < 8; ++j)
                    acc[i][j] = fmaf(av[i], bv[j], acc[i][j]);
        }
    }

#pragma unroll
    for (int ih = 0; ih < 2; ++ih)
#pragma unroll
        for (int i = 0; i < 4; ++i) {
            const int row = rp * 128 + rg + i + ih * 64;
#pragma unroll
            for (int jh = 0; jh < 2; ++jh) {
                const int col = cb * 128 + cg + jh * 64;
                float4 o;
                o.x = acc[ih * 4 + i][jh * 4 + 0];
                o.y = acc[ih * 4 + i][jh * 4 + 1];
                o.z = acc[ih * 4 + i][jh * 4 + 2];
                o.w = acc[ih * 4 + i][jh * 4 + 3];
                if (BIAS) {
                    o.x += bias[col + 0]; o.y += bias[col + 1];
                    o.z += bias[col + 2]; o.w += bias[col + 3];
                }
                *(float4*)&Cb[(size_t)row * 512 + col] = o;
            }
        }
}

// ---------------------------------------------------------------------------
// LIF over 128 steps for Q/K/V (one dispatch, br = branch), emitting bitmasks.
// ---------------------------------------------------------------------------
__global__ __launch_bounds__(256) void lif_mask3(
    const float* __restrict__ U0, const float* __restrict__ U1,
    const float* __restrict__ U2,
    const float* __restrict__ wq, const float* __restrict__ wk,
    const float* __restrict__ wv, ull* __restrict__ M)
{
    const int br = blockIdx.x / 392;
    const int blk = blockIdx.x - br * 392;
    const int i = blk * 256 + threadIdx.x;
    const float* U = (br == 0) ? U0 : (br == 1 ? U1 : U2);
    const float wv_ = (br == 0) ? wq[0] : (br == 1 ? wk[0] : wv[0]);
    const float sg = 1.0f / (1.0f + expf(-wv_));
    ull* Mw = M + (size_t)br * 200704 + ((i >> 6) & 7) * 196 + (i >> 9);
    float v = 0.0f;
    for (int t = 0; t < 128; ++t) {
        const float x = U[(size_t)t * NC + i];
        const float h = __fadd_rn(v, __fmul_rn(__fsub_rn(x, v), sg));
        const bool sp = (h >= 1.0f);
        const ull m = __ballot(sp);
        if ((threadIdx.x & 63) == 0) Mw[(size_t)t * 1568] = m;
        v = sp ? 0.0f : h;
    }
}

// ---------------------------------------------------------------------------
// proj LIF: float spikes out.
// ---------------------------------------------------------------------------
__global__ __launch_bounds__(256) void lif_out(const float* __restrict__ U,
                                               const float* __restrict__ wp,
                                               float* __restrict__ out)
{
    const int i = blockIdx.x * 256 + threadIdx.x;
    const float sg = 1.0f / (1.0f + expf(-wp[0]));
    float v = 0.0f;
    for (int t = 0; t < 128; ++t) {
        const float x = U[(size_t)t * NC + i];
        const float h = __fadd_rn(v, __fmul_rn(__fsub_rn(x, v), sg));
        const bool sp = (h >= 1.0f);
        out[(size_t)t * NC + i] = sp ? 1.0f : 0.0f;
        v = sp ? 0.0f : h;
    }
}

// ---------------------------------------------------------------------------
// Fused attention + attn_lif (validated rounds 3-8, unchanged).
// ---------------------------------------------------------------------------
__global__ __launch_bounds__(256) void attn_fused(const ull* __restrict__ Qm,
                                                  const ull* __restrict__ Km,
                                                  const ull* __restrict__ Vm,
                                                  const float* __restrict__ wa,
                                                  float* __restrict__ Y)
{
    const int b = blockIdx.x >> 3;
    const int h = blockIdx.x & 7;
    const int tid = threadIdx.x;
    const int w = tid >> 6;
    const int lane = tid & 63;

    __shared__ ull qrow[256], krow[256], vrow[256];
    __shared__ ull kcol[64][5], vcol[64][5];
    __shared__ ushort G[64][64];
    __shared__ float vstate[196][64];
    __shared__ ull sbm[208];

    const float sg = 1.0f / (1.0f + expf(-wa[0]));

    for (int t = 0; t < 4; ++t) {
        const int tb = t * 32 + b;
        const size_t mb = (size_t)tb * 1568 + (size_t)h * 196;
        if (tid < 196) {
            qrow[tid] = Qm[mb + tid];
            krow[tid] = Km[mb + tid];
            vrow[tid] = Vm[mb + tid];
        } else {
            qrow[tid] = 0; krow[tid] = 0; vrow[tid] = 0;
        }
        __syncthreads();

        {
            ull kc = 0, vc = 0;
#pragma unroll 8
            for (int m = 0; m < 64; ++m) {
                kc |= ((krow[w * 64 + m] >> lane) & 1ull) << m;
                vc |= ((vrow[w * 64 + m] >> lane) & 1ull) << m;
            }
            kcol[lane][w] = kc; vcol[lane][w] = vc;
        }
        __syncthreads();

        for (int p = tid; p < 4096; p += 256) {
            const int d1 = p >> 6, d2 = p & 63;
            const int g = __popcll(kcol[d1][0] & vcol[d2][0]) +
                          __popcll(kcol[d1][1] & vcol[d2][1]) +
                          __popcll(kcol[d1][2] & vcol[d2][2]) +
                          __popcll(kcol[d1][3] & vcol[d2][3]);
            G[d1][d2] = (ushort)g;
        }
        __syncthreads();

        {
            int r = 49 * w;
            const int rend = r + 49;
            for (; r + 1 < rend; r += 2) {
                const ull q0 = qrow[r], q1 = qrow[r + 1];
                const uint a0 = (uint)q0, a1 = (uint)(q0 >> 32);
                const uint b0 = (uint)q1, b1 = (uint)(q1 >> 32);
                uint s0 = 0, s1 = 0;
#pragma unroll
                for (int d = 0; d < 32; ++d) {
                    const uint g = G[d][lane];
                    s0 += ((a0 >> d) & 1u) * g;
                    s1 += ((b0 >> d) & 1u) * g;
                }
#pragma unroll
                for (int d = 0; d < 32; ++d) {
                    const uint g = G[32 + d][lane];
                    s0 += ((a1 >> d) & 1u) * g;
                    s1 += ((b1 >> d) & 1u) * g;
                }
                const float y0 = (float)s0 * 0.125f;
                const float v0 = t ? vstate[r][lane] : 0.0f;
                const float h0 = __fadd_rn(v0, __fmul_rn(__fsub_rn(y0, v0), sg));
                const bool sp0 = h0 >= 1.0f;
                vstate[r][lane] = sp0 ? 0.0f : h0;
                const ull m0 = __ballot(sp0);
                const float y1 = (float)s1 * 0.125f;
                const float v1 = t ? vstate[r + 1][lane] : 0.0f;
                const float h1 = __fadd_rn(v1, __fmul_rn(__fsub_rn(y1, v1), sg));
                const bool sp1 = h1 >= 1.0f;
                vstate[r + 1][lane] = sp1 ? 0.0f : h1;
                const ull m1 = __ballot(sp1);
                if (lane == 0) { sbm[r] = m0; sbm[r + 1] = m1; }
            }
            {
                const ull q0 = qrow[r];
                const uint a0 = (uint)q0, a1 = (uint)(q0 >> 32);
                uint s0 = 0;
#pragma unroll
                for (int d = 0; d < 32; ++d) s0 += ((a0 >> d) & 1u) * (uint)G[d][lane];
#pragma unroll
                for (int d = 0; d < 32; ++d) s0 += ((a1 >> d) & 1u) * (uint)G[32 + d][lane];
                const float y0 = (float)s0 * 0.125f;
                const float v0 = t ? vstate[r][lane] : 0.0f;
                const float h0 = __fadd_rn(v0, __fmul_rn(__fsub_rn(y0, v0), sg));
                const bool sp0 = h0 >= 1.0f;
                vstate[r][lane] = sp0 ? 0.0f : h0;
                const ull m0 = __ballot(sp0);
                if (lane == 0) sbm[r] = m0;
            }
        }
        __syncthreads();

        const size_t yb = (size_t)tb * NC + (size_t)h * 12544;
        for (int f = tid; f < 12544; f += 256) {
            const int e = f / 196;
            const int r2 = f - e * 196;
            Y[yb + f] = ((sbm[r2] >> e) & 1ull) ? 1.0f : 0.0f;
        }
        __syncthreads();
    }
}

// ---------------------------------------------------------------------------
// Workspace (158,957,568 B):
//   u0/u1/u2 : fp32 [128][196][512] 51,380,224 B each
//   Qm/Km/Vm : [128][8][196] ull, 1,605,632 B each
// Aliases: ySc = u0 (dead after lif_mask3); proj-u = u1 (dead after attn).
// ---------------------------------------------------------------------------
extern "C" void kernel_launch(void* const* d_in, const int* in_sizes, int n_in,
                              void* d_out, int out_size, void* d_ws, size_t ws_size,
                              hipStream_t stream) {
    const float* x  = (const float*)d_in[0];
    const float* Wq = (const float*)d_in[1];
    const float* Wk = (const float*)d_in[2];
    const float* Wv = (const float*)d_in[3];
    const float* Wp = (const float*)d_in[4];
    const float* bp = (const float*)d_in[5];
    const float* wq = (const float*)d_in[6];
    const float* wk = (const float*)d_in[7];
    const float* wv = (const float*)d_in[8];
    const float* wa = (const float*)d_in[9];
    const float* wp = (const float*)d_in[10];
    float* out = (float*)d_out;

    char* ws = (char*)d_ws;
    float* u0 = (float*)ws;
    float* u1 = (float*)(ws + (size_t)51380224);
    float* u2 = (float*)(ws + (size_t)2 * 51380224);
    ull* Qm   = (ull*)(ws + (size_t)3 * 51380224);
    ull* Km   = Qm + 200704;
    ull* Vm   = Km + 200704;
    float* ySc = u0;   // attn output aliases u0
    float* up  = u1;   // proj GEMM output aliases u1

    // Q/K/V GEMMs: one merged dispatch, 16x8 microtile, 1176 blocks
    gemm16<3, false><<<1176, 256, 0, stream>>>(x, Wq, Wk, Wv, nullptr,
                                               u0, u1, u2);
    // LIF -> spike bitmasks
    lif_mask3<<<1176, 256, 0, stream>>>(u0, u1, u2, wq, wk, wv, Qm);

    // Attention + attn_lif -> scrambled float spikes
    attn_fused<<<256, 256, 0, stream>>>(Qm, Km, Vm, wa, ySc);

    // Projection + bias (8x8 body, 784 blocks)
    gemm_nt<1, true><<<784, 256, 0, stream>>>(ySc, Wp, nullptr, nullptr, bp,
                                              up, nullptr, nullptr);
    // proj LIF -> output spikes
    lif_out<<<392, 256, 0, stream>>>(up, wp, out);
}